// Round 6
// baseline (29.099 us; speedup 1.0000x reference)
//
#include <hip/hip_runtime.h>
#include <hip/hip_bf16.h>

// GMM 2D activation: out = x * gmm2d(x)
// out[o] = x[o] * sum_k exp(-0.5 diff^T IVC_k diff) * exp(log_weights[k][o])
// Max-subtraction cancels exactly; IVC is PSD so exponent <= 0 (safe).
// exp via native v_exp_f32 with log2e folded into quadratic coefficients.
//
// R6: full streaming semantics — NONTEMPORAL on both loads and stores.
// Every replay sweeps 67MB in + 67MB out; with cached accesses the read
// stream thrashes the 4MiB/XCD L2 and its miss-fills evict dirty output
// lines (extra fabric round-trip). nt on both streams = no L2 allocation,
// matching the 6.7 TB/s fill kernel's cache behavior.

#define LOG2E 1.4426950408889634f

typedef float f32x2 __attribute__((ext_vector_type(2)));
typedef float f32x4 __attribute__((ext_vector_type(4)));

template <int ITERS>
__global__ __launch_bounds__(256) void gmm2d_act_kernel(
    const f32x4* __restrict__ x,
    const float* __restrict__ means,   // (K,2)
    const float* __restrict__ ivc,     // (K,2,2)
    const float* __restrict__ lw,      // (K,2)
    f32x4* __restrict__ out,
    int n4)
{
    // Broadcast-load the 28 GMM parameters; splat into packed float2 regs.
    f32x2 M0[4], M1[4], Aq[4], Bq[4], Cq[4], W0[4], W1[4];
#pragma unroll
    for (int k = 0; k < 4; ++k) {
        float m0 = means[2*k + 0];
        float m1 = means[2*k + 1];
        float aq = -0.5f * LOG2E *  ivc[4*k + 0];
        float bq = -0.5f * LOG2E * (ivc[4*k + 1] + ivc[4*k + 2]);
        float cq = -0.5f * LOG2E *  ivc[4*k + 3];
        float w0 = expf(lw[2*k + 0]);   // precise expf, once per thread
        float w1 = expf(lw[2*k + 1]);
        M0[k] = (f32x2){m0, m0};  M1[k] = (f32x2){m1, m1};
        Aq[k] = (f32x2){aq, aq};  Bq[k] = (f32x2){bq, bq};
        Cq[k] = (f32x2){cq, cq};
        W0[k] = (f32x2){w0, w0};  W1[k] = (f32x2){w1, w1};
    }

    // Block-contiguous chunk: block b owns [b*256*ITERS, (b+1)*256*ITERS).
    const int base = blockIdx.x * (blockDim.x * ITERS) + threadIdx.x;

    if (base + (ITERS - 1) * blockDim.x < n4) {
        f32x4 v[ITERS];
#pragma unroll
        for (int it = 0; it < ITERS; ++it)
            v[it] = __builtin_nontemporal_load(&x[base + it * blockDim.x]);

#pragma unroll
        for (int it = 0; it < ITERS; ++it) {
            // Pack pair0=(x,y), pair1=(z,w) into float2 lanes.
            f32x2 X0 = {v[it].x, v[it].z};
            f32x2 X1 = {v[it].y, v[it].w};
            f32x2 S0 = {0.f, 0.f}, S1 = {0.f, 0.f};
#pragma unroll
            for (int k = 0; k < 4; ++k) {
                f32x2 D0 = X0 - M0[k];
                f32x2 D1 = X1 - M1[k];
                f32x2 T  = __builtin_elementwise_fma(Bq[k], D1, Aq[k] * D0);
                f32x2 Q  = __builtin_elementwise_fma(Cq[k] * D1, D1, D0 * T);
                f32x2 E  = {__builtin_amdgcn_exp2f(Q.x),
                            __builtin_amdgcn_exp2f(Q.y)};
                S0 = __builtin_elementwise_fma(E, W0[k], S0);
                S1 = __builtin_elementwise_fma(E, W1[k], S1);
            }
            f32x4 r = {v[it].x * S0.x, v[it].y * S1.x,
                       v[it].z * S0.y, v[it].w * S1.y};
            __builtin_nontemporal_store(r, &out[base + it * blockDim.x]);
        }
    } else {
        // Tail path (unused for the 2^22 size; kept for safety).
        for (int it = 0; it < ITERS; ++it) {
            int i = base + it * blockDim.x;
            if (i >= n4) break;
            f32x4 v = x[i];
            f32x2 X0 = {v.x, v.z};
            f32x2 X1 = {v.y, v.w};
            f32x2 S0 = {0.f, 0.f}, S1 = {0.f, 0.f};
#pragma unroll
            for (int k = 0; k < 4; ++k) {
                f32x2 D0 = X0 - M0[k];
                f32x2 D1 = X1 - M1[k];
                f32x2 T  = __builtin_elementwise_fma(Bq[k], D1, Aq[k] * D0);
                f32x2 Q  = __builtin_elementwise_fma(Cq[k] * D1, D1, D0 * T);
                f32x2 E  = {__builtin_amdgcn_exp2f(Q.x),
                            __builtin_amdgcn_exp2f(Q.y)};
                S0 = __builtin_elementwise_fma(E, W0[k], S0);
                S1 = __builtin_elementwise_fma(E, W1[k], S1);
            }
            f32x4 r = {v.x * S0.x, v.y * S1.x, v.z * S0.y, v.w * S1.y};
            out[i] = r;
        }
    }
}

extern "C" void kernel_launch(void* const* d_in, const int* in_sizes, int n_in,
                              void* d_out, int out_size, void* d_ws, size_t ws_size,
                              hipStream_t stream) {
    const f32x4* x     = (const f32x4*)d_in[0];   // (2,4096,2048) fp32
    const float* means = (const float*)d_in[1];    // (1,1,4,2)
    const float* ivc   = (const float*)d_in[2];    // (4,2,2)
    const float* lw    = (const float*)d_in[3];    // (1,1,1,4,2)
    f32x4* out = (f32x4*)d_out;

    const int n4 = out_size / 4;                   // 4,194,304 float4s (2^22)
    const int block = 256;
    const int per_block = block * 8;               // 2048 float4s = 32 KB

    const int grid = (n4 + per_block - 1) / per_block;   // 2048 for 2^22
    gmm2d_act_kernel<8><<<grid, block, 0, stream>>>(x, means, ivc, lw, out, n4);
}

// Round 7
// 26.507 us; speedup vs baseline: 1.0978x; 1.0978x over previous
//
#include <hip/hip_runtime.h>
#include <hip/hip_bf16.h>

// GMM 2D activation: out = x * gmm2d(x)
// out[o] = x[o] * sum_k exp(-0.5 diff^T IVC_k diff) * exp(log_weights[k][o])
// Max-subtraction cancels exactly; IVC is PSD so exponent <= 0 (safe).
// exp via native v_exp_f32 with log2e folded into quadratic coefficients.
//
// R7: cached LOADS (R6 proved nt loads lose L3 read-service: 26.4->29.1us)
//   + NONTEMPORAL STORES (output is never re-read; don't let the write
//     stream allocate L3 lines and evict the replay-resident 67MB input)
//   + block-contiguous chunks.

#define LOG2E 1.4426950408889634f

typedef float f32x2 __attribute__((ext_vector_type(2)));
typedef float f32x4 __attribute__((ext_vector_type(4)));

template <int ITERS>
__global__ __launch_bounds__(256) void gmm2d_act_kernel(
    const f32x4* __restrict__ x,
    const float* __restrict__ means,   // (K,2)
    const float* __restrict__ ivc,     // (K,2,2)
    const float* __restrict__ lw,      // (K,2)
    f32x4* __restrict__ out,
    int n4)
{
    // Broadcast-load the 28 GMM parameters; splat into packed float2 regs.
    f32x2 M0[4], M1[4], Aq[4], Bq[4], Cq[4], W0[4], W1[4];
#pragma unroll
    for (int k = 0; k < 4; ++k) {
        float m0 = means[2*k + 0];
        float m1 = means[2*k + 1];
        float aq = -0.5f * LOG2E *  ivc[4*k + 0];
        float bq = -0.5f * LOG2E * (ivc[4*k + 1] + ivc[4*k + 2]);
        float cq = -0.5f * LOG2E *  ivc[4*k + 3];
        float w0 = expf(lw[2*k + 0]);   // precise expf, once per thread
        float w1 = expf(lw[2*k + 1]);
        M0[k] = (f32x2){m0, m0};  M1[k] = (f32x2){m1, m1};
        Aq[k] = (f32x2){aq, aq};  Bq[k] = (f32x2){bq, bq};
        Cq[k] = (f32x2){cq, cq};
        W0[k] = (f32x2){w0, w0};  W1[k] = (f32x2){w1, w1};
    }

    // Block-contiguous chunk: block b owns [b*256*ITERS, (b+1)*256*ITERS).
    const int base = blockIdx.x * (blockDim.x * ITERS) + threadIdx.x;

    if (base + (ITERS - 1) * blockDim.x < n4) {
        f32x4 v[ITERS];
#pragma unroll
        for (int it = 0; it < ITERS; ++it)
            v[it] = x[base + it * blockDim.x];     // cached: L3 read-service

#pragma unroll
        for (int it = 0; it < ITERS; ++it) {
            // Pack pair0=(x,y), pair1=(z,w) into float2 lanes.
            f32x2 X0 = {v[it].x, v[it].z};
            f32x2 X1 = {v[it].y, v[it].w};
            f32x2 S0 = {0.f, 0.f}, S1 = {0.f, 0.f};
#pragma unroll
            for (int k = 0; k < 4; ++k) {
                f32x2 D0 = X0 - M0[k];
                f32x2 D1 = X1 - M1[k];
                f32x2 T  = __builtin_elementwise_fma(Bq[k], D1, Aq[k] * D0);
                f32x2 Q  = __builtin_elementwise_fma(Cq[k] * D1, D1, D0 * T);
                f32x2 E  = {__builtin_amdgcn_exp2f(Q.x),
                            __builtin_amdgcn_exp2f(Q.y)};
                S0 = __builtin_elementwise_fma(E, W0[k], S0);
                S1 = __builtin_elementwise_fma(E, W1[k], S1);
            }
            f32x4 r = {v[it].x * S0.x, v[it].y * S1.x,
                       v[it].z * S0.y, v[it].w * S1.y};
            // nt store: output never re-read; keep it out of L3 so the
            // input stays resident across graph replays.
            __builtin_nontemporal_store(r, &out[base + it * blockDim.x]);
        }
    } else {
        // Tail path (unused for the 2^22 size; kept for safety).
        for (int it = 0; it < ITERS; ++it) {
            int i = base + it * blockDim.x;
            if (i >= n4) break;
            f32x4 v = x[i];
            f32x2 X0 = {v.x, v.z};
            f32x2 X1 = {v.y, v.w};
            f32x2 S0 = {0.f, 0.f}, S1 = {0.f, 0.f};
#pragma unroll
            for (int k = 0; k < 4; ++k) {
                f32x2 D0 = X0 - M0[k];
                f32x2 D1 = X1 - M1[k];
                f32x2 T  = __builtin_elementwise_fma(Bq[k], D1, Aq[k] * D0);
                f32x2 Q  = __builtin_elementwise_fma(Cq[k] * D1, D1, D0 * T);
                f32x2 E  = {__builtin_amdgcn_exp2f(Q.x),
                            __builtin_amdgcn_exp2f(Q.y)};
                S0 = __builtin_elementwise_fma(E, W0[k], S0);
                S1 = __builtin_elementwise_fma(E, W1[k], S1);
            }
            f32x4 r = {v.x * S0.x, v.y * S1.x, v.z * S0.y, v.w * S1.y};
            out[i] = r;
        }
    }
}

extern "C" void kernel_launch(void* const* d_in, const int* in_sizes, int n_in,
                              void* d_out, int out_size, void* d_ws, size_t ws_size,
                              hipStream_t stream) {
    const f32x4* x     = (const f32x4*)d_in[0];   // (2,4096,2048) fp32
    const float* means = (const float*)d_in[1];    // (1,1,4,2)
    const float* ivc   = (const float*)d_in[2];    // (4,2,2)
    const float* lw    = (const float*)d_in[3];    // (1,1,1,4,2)
    f32x4* out = (f32x4*)d_out;

    const int n4 = out_size / 4;                   // 4,194,304 float4s (2^22)
    const int block = 256;
    const int per_block = block * 8;               // 2048 float4s = 32 KB

    const int grid = (n4 + per_block - 1) / per_block;   // 2048 for 2^22
    gmm2d_act_kernel<8><<<grid, block, 0, stream>>>(x, means, ivc, lw, out, n4);
}